// Round 15
// baseline (288.453 us; speedup 1.0000x reference)
//
#include <hip/hip_runtime.h>
#include <hip/hip_bf16.h>
#include <hip/hip_fp16.h>

#define Bn 8
#define Tn 4096
#define En 2048
#define Hn 128

typedef __attribute__((ext_vector_type(8))) short bf16x8;
typedef __attribute__((ext_vector_type(4))) float f32x4;
typedef __attribute__((ext_vector_type(4))) unsigned int u32x4;

typedef const __attribute__((address_space(1))) unsigned int* gptr_t;
typedef __attribute__((address_space(3))) unsigned int* lptr_t;

static __device__ __forceinline__ void gload16(const void* g, void* l) {
    __builtin_amdgcn_global_load_lds((gptr_t)g, (lptr_t)l, 16, 0, 0);
}

static __device__ __forceinline__ unsigned short f2bf(float f) {
    union { float f; unsigned u; } v; v.f = f;
    unsigned r = v.u + 0x7FFFu + ((v.u >> 16) & 1u);
    return (unsigned short)(r >> 16);
}
static __device__ __forceinline__ float b2f(unsigned short bits) {
    union { unsigned u; float f; } v; v.u = ((unsigned)bits) << 16;
    return v.f;
}
static __device__ __forceinline__ unsigned cvtpk(float lo, float hi) {
    unsigned r;
    asm volatile("v_cvt_pk_bf16_f32 %0, %1, %2" : "=v"(r) : "v"(lo), "v"(hi));
    return r;
}

#define MFMA16(a, b, c) __builtin_amdgcn_mfma_f32_16x16x32_bf16((a), (b), (c), 0, 0, 0)
#define EXP2F(x) __builtin_amdgcn_exp2f(x)
#define WAIT_VM_PUB(N) do { asm volatile("s_waitcnt vmcnt(" #N ")" ::: "memory"); \
                            __builtin_amdgcn_sched_barrier(0); \
                            __builtin_amdgcn_s_barrier(); \
                            __builtin_amdgcn_sched_barrier(0); } while (0)
#define LGKM_BARRIER() do { asm volatile("s_waitcnt lgkmcnt(0)" ::: "memory"); \
                            __builtin_amdgcn_s_barrier(); \
                            __builtin_amdgcn_sched_barrier(0); } while (0)

// ---------------- K0: transpose+convert weights, fold SCALE*log2e into Wq ----
__global__ __launch_bounds__(256) void prep_w(const float* __restrict__ Wq,
                                              const float* __restrict__ Wk,
                                              const float* __restrict__ Wv,
                                              unsigned short* __restrict__ Wt) {
    int idx = blockIdx.x * 256 + threadIdx.x;
    int w = idx / (En * Hn);
    int rem = idx - w * (En * Hn);
    int kx = rem >> 7;
    int n  = rem & 127;
    const float* W = (w == 0) ? Wq : (w == 1) ? Wk : Wv;
    float f = W[rem];
    if (w == 0) f *= (0.17677669529663687f * 1.4426950408889634f); // 32^-0.5 * log2(e)
    Wt[(size_t)w * En * Hn + (size_t)n * En + kx] = f2bf(f);
}

// ---------------- K1: qkv projection — A converted at STAGE time -------------
// BM=128, BN=128, BK=64, 4 waves. A: x fp32 -> regs -> cvt_pk -> bf16 LDS dbuf
// (swizzled write, clean b128 reads). B: bf16 gload16 dbuf (source-preswizzled).
// One barrier per step: issue A(t+1)regs + B(t+1)gload -> MFMA(t) -> vmcnt(4)
// -> cvt+ds_write -> vmcnt(0)+lgkm(0)+barrier.
__global__ __launch_bounds__(256, 2) void qkv_mfma(const float* __restrict__ x,
                                                   const unsigned short* __restrict__ Wt,
                                                   unsigned short* __restrict__ qs,
                                                   unsigned short* __restrict__ ks,
                                                   unsigned short* __restrict__ vT) {
    __shared__ __align__(16) unsigned short Al[2][128][64]; // 32 KB (bf16, dbuf)
    __shared__ __align__(16) unsigned short Bl[2][128][64]; // 32 KB
    const int bid = blockIdx.x;
    const int w = bid % 3;
    const int m0 = (bid / 3) * 128;
    const int b = m0 >> 12;
    const int tb = m0 & (Tn - 1);
    const int t = threadIdx.x;
    const int lane = t & 63, wid = t >> 6;
    const int wr = (wid >> 1) * 64, wc = (wid & 1) * 64;
    const int fr = lane & 15, fq = lane >> 4;
    const unsigned short* Wb = Wt + (size_t)w * En * Hn;
    // A staging: grp=t>>4 owns rows grp*8+j (j<8); ln=t&15 owns float4 col ln
    const int agrp = t >> 4, aln = t & 15;
    // B staging: 16 segs of 8 rows x 8 chunks
    const int bR = lane >> 3, bC = lane & 7;

    // prologue: A(0) reg->cvt->LDS, B(0) gload
    #pragma unroll
    for (int j = 0; j < 8; ++j) {
        int row = agrp * 8 + j;
        float4 v = *reinterpret_cast<const float4*>(&x[(size_t)(m0 + row) * En + aln * 4]);
        int c = (aln >> 1) ^ ((row ^ (row >> 3)) & 7);
        *reinterpret_cast<uint2*>((char*)&Al[0][0][0] + row * 128 + c * 16 + (aln & 1) * 8)
            = make_uint2(cvtpk(v.x, v.y), cvtpk(v.z, v.w));
    }
    #pragma unroll
    for (int s_ = 0; s_ < 4; ++s_) {
        int seg = wid * 4 + s_;
        int r = seg * 8 + bR;
        gload16(&Wb[(size_t)r * En + ((bC ^ (r & 7)) * 8)],
                (char*)&Bl[0][0][0] + seg * 1024 + lane * 16);
    }
    asm volatile("s_waitcnt vmcnt(0) lgkmcnt(0)" ::: "memory");
    __builtin_amdgcn_s_barrier();
    __builtin_amdgcn_sched_barrier(0);

    f32x4 acc[4][4] = {};
    for (int s = 0; s < 32; ++s) {
        const int cur = s & 1;
        const int kn = ((s + 1) & 31) * 64;   // wrap: final prefetch unused
        // 1. issue A(t+1) -> regs (8 vmem, full-line coalesced per row)
        float4 ar_[8];
        #pragma unroll
        for (int j = 0; j < 8; ++j) {
            int row = agrp * 8 + j;
            ar_[j] = *reinterpret_cast<const float4*>(&x[(size_t)(m0 + row) * En + kn + aln * 4]);
        }
        __builtin_amdgcn_sched_barrier(0);   // keep A-issue before B-issue (vmcnt order)
        // 2. issue B(t+1) gloads into Bl[alt] (4 vmem)
        #pragma unroll
        for (int s_ = 0; s_ < 4; ++s_) {
            int seg = wid * 4 + s_;
            int r = seg * 8 + bR;
            gload16(&Wb[(size_t)r * En + kn + ((bC ^ (r & 7)) * 8)],
                    (char*)&Bl[cur ^ 1][0][0] + seg * 1024 + lane * 16);
        }
        __builtin_amdgcn_sched_barrier(0);
        // 3. MFMA on [cur]
        #pragma unroll
        for (int ksub = 0; ksub < 2; ++ksub) {
            bf16x8 av[4], bv[4];
            #pragma unroll
            for (int mi = 0; mi < 4; ++mi) {
                int row = wr + mi * 16 + fr;
                int ch = (ksub * 4 + fq) ^ ((row ^ (row >> 3)) & 7);
                av[mi] = *reinterpret_cast<const bf16x8*>(
                    (const char*)&Al[cur][0][0] + row * 128 + ch * 16);
            }
            #pragma unroll
            for (int ni = 0; ni < 4; ++ni) {
                int row = wc + ni * 16 + fr;
                int ch = (ksub * 4 + fq) ^ (row & 7);
                bv[ni] = *reinterpret_cast<const bf16x8*>(
                    (const char*)&Bl[cur][0][0] + row * 128 + ch * 16);
            }
            #pragma unroll
            for (int mi = 0; mi < 4; ++mi)
                #pragma unroll
                for (int ni = 0; ni < 4; ++ni)
                    acc[mi][ni] = MFMA16(av[mi], bv[ni], acc[mi][ni]);
        }
        // 4. A regs ready (4 B gloads still in flight)
        asm volatile("s_waitcnt vmcnt(4)" ::: "memory");
        __builtin_amdgcn_sched_barrier(0);
        // 5. cvt + write A(t+1) -> Al[alt]
        #pragma unroll
        for (int j = 0; j < 8; ++j) {
            int row = agrp * 8 + j;
            int c = (aln >> 1) ^ ((row ^ (row >> 3)) & 7);
            *reinterpret_cast<uint2*>((char*)&Al[cur ^ 1][0][0] + row * 128 + c * 16 + (aln & 1) * 8)
                = make_uint2(cvtpk(ar_[j].x, ar_[j].y), cvtpk(ar_[j].z, ar_[j].w));
        }
        // 6. single barrier: B landed, A writes visible, [cur] reads retired
        asm volatile("s_waitcnt vmcnt(0) lgkmcnt(0)" ::: "memory");
        __builtin_amdgcn_s_barrier();
        __builtin_amdgcn_sched_barrier(0);
    }

    if (w < 2) {
        unsigned short* out = (w == 0) ? qs : ks;
        #pragma unroll
        for (int mi = 0; mi < 4; ++mi)
            #pragma unroll
            for (int ni = 0; ni < 4; ++ni)
                #pragma unroll
                for (int r = 0; r < 4; ++r) {
                    int row = m0 + wr + mi * 16 + fq * 4 + r;
                    int col = wc + ni * 16 + fr;
                    out[(size_t)row * Hn + col] = f2bf(acc[mi][ni][r]);
                }
    } else {
        #pragma unroll
        for (int mi = 0; mi < 4; ++mi)
            #pragma unroll
            for (int ni = 0; ni < 4; ++ni)
                #pragma unroll
                for (int r = 0; r < 4; ++r) {
                    int tt = tb + wr + mi * 16 + fq * 4 + r;
                    int h  = wc + ni * 16 + fr;
                    vT[((size_t)b * Hn + h) * Tn + tt] = f2bf(acc[mi][ni][r]);
                }
    }
}

// ---------------- K2: column stats — 128 stationary keys, Q double-buffered --
__global__ __launch_bounds__(256, 2) void stats_qk(const unsigned short* __restrict__ qs,
                                                   const unsigned short* __restrict__ ks,
                                                   float2* __restrict__ part) {
    // LDS: K 0..32768 | Q dbuf 32768..65536
    __shared__ __align__(16) char smem[65536];
    const int bid = blockIdx.x;
    const int b = bid & 7;
    const int rest = bid >> 3;                // 0..63
    const int kt = rest & 31;
    const int qh = rest >> 5;
    const int k0 = kt * 128;
    const unsigned short* qb = qs + (size_t)b * Tn * Hn;
    const unsigned short* kb = ks + (size_t)b * Tn * Hn;
    const int t = threadIdx.x;
    const int lane = t & 63, wid = t >> 6;
    const int wk = wid >> 1, wq = wid & 1;
    const int fr = lane & 15, fq = lane >> 4;
    const int srow = t >> 4, schk = t & 15;

    #pragma unroll
    for (int it = 0; it < 8; ++it) {
        int r = it * 16 + srow;
        gload16(&kb[(size_t)(k0 + r) * Hn + ((schk ^ (r & 15)) * 8)],
                smem + it * 4096 + t * 16);
    }
    #pragma unroll
    for (int it = 0; it < 4; ++it) {
        int r = it * 16 + srow;
        gload16(&qb[(size_t)(qh * 2048 + r) * Hn + ((schk ^ (r & 15)) * 8)],
                smem + 32768 + it * 4096 + t * 16);
    }
    __syncthreads();
    bf16x8 av[4][4];
    #pragma unroll
    for (int mi = 0; mi < 4; ++mi)
        #pragma unroll
        for (int kc = 0; kc < 4; ++kc) {
            int row = wk * 64 + mi * 16 + fr;
            int ch = (kc * 4 + fq) ^ (row & 15);
            av[mi][kc] = *reinterpret_cast<const bf16x8*>(smem + row * 256 + ch * 16);
        }

    float m[4][4], l[4][4];
    #pragma unroll
    for (int mi = 0; mi < 4; ++mi)
        #pragma unroll
        for (int r = 0; r < 4; ++r) { m[mi][r] = -INFINITY; l[mi][r] = 0.f; }

    for (int step = 0; step < 32; ++step) {
        const int cur = step & 1;
        const int qn = qh * 2048 + ((step + 1) & 31) * 64;
        #pragma unroll
        for (int it = 0; it < 4; ++it) {
            int r = it * 16 + srow;
            gload16(&qb[(size_t)(qn + r) * Hn + ((schk ^ (r & 15)) * 8)],
                    smem + 32768 + (cur ^ 1) * 16384 + it * 4096 + t * 16);
        }
        WAIT_VM_PUB(4);
        const char* Qc = smem + 32768 + cur * 16384;
        f32x4 acc[4][2] = {};
        __builtin_amdgcn_s_setprio(1);
        #pragma unroll
        for (int kc = 0; kc < 4; ++kc) {
            bf16x8 bv[2];
            #pragma unroll
            for (int ni = 0; ni < 2; ++ni) {
                int row = wq * 32 + ni * 16 + fr;
                int ch = (kc * 4 + fq) ^ (row & 15);
                bv[ni] = *reinterpret_cast<const bf16x8*>(Qc + row * 256 + ch * 16);
            }
            #pragma unroll
            for (int mi = 0; mi < 4; ++mi)
                #pragma unroll
                for (int ni = 0; ni < 2; ++ni)
                    acc[mi][ni] = MFMA16(av[mi][kc], bv[ni], acc[mi][ni]);
        }
        __builtin_amdgcn_s_setprio(0);
        #pragma unroll
        for (int mi = 0; mi < 4; ++mi)
            #pragma unroll
            for (int r = 0; r < 4; ++r) {
                float v0 = acc[mi][0][r], v1 = acc[mi][1][r];
                float mn = fmaxf(m[mi][r], fmaxf(v0, v1));
                l[mi][r] = l[mi][r] * EXP2F(m[mi][r] - mn) + EXP2F(v0 - mn) + EXP2F(v1 - mn);
                m[mi][r] = mn;
            }
        LGKM_BARRIER();
    }
    #pragma unroll
    for (int off = 1; off <= 8; off <<= 1) {
        #pragma unroll
        for (int mi = 0; mi < 4; ++mi)
            #pragma unroll
            for (int r = 0; r < 4; ++r) {
                float mo = __shfl_xor(m[mi][r], off);
                float lo = __shfl_xor(l[mi][r], off);
                float mn = fmaxf(m[mi][r], mo);
                l[mi][r] = l[mi][r] * EXP2F(m[mi][r] - mn) + lo * EXP2F(mo - mn);
                m[mi][r] = mn;
            }
    }
    if (fr == 0) {
        #pragma unroll
        for (int mi = 0; mi < 4; ++mi)
            #pragma unroll
            for (int r = 0; r < 4; ++r) {
                int k = k0 + wk * 64 + mi * 16 + fq * 4 + r;
                part[((size_t)b * Tn + k) * 4 + qh * 2 + wq] = make_float2(m[mi][r], l[mi][r]);
            }
    }
}

// ---------------- K3: combine 4 partials -> mr[b][k] = m + log2(l) -----------
__global__ __launch_bounds__(256) void stats_comb(const float2* __restrict__ part,
                                                  float* __restrict__ mr) {
    int g = blockIdx.x * 256 + threadIdx.x;   // 8*4096
    const float2* pp = part + (size_t)g * 4;
    float2 p0 = pp[0], p1 = pp[1], p2 = pp[2], p3 = pp[3];
    float M = fmaxf(fmaxf(p0.x, p1.x), fmaxf(p2.x, p3.x));
    float L = p0.y * EXP2F(p0.x - M) + p1.y * EXP2F(p1.x - M) +
              p2.y * EXP2F(p2.x - M) + p3.y * EXP2F(p3.x - M);
    mr[g] = M + __log2f(L);
}

// ---------------- K3b: vn[b][h][t] = v * 2^(-mr[b][t]) -----------------------
__global__ __launch_bounds__(256) void scale_v(const unsigned short* __restrict__ vT,
                                               const float* __restrict__ mr,
                                               unsigned short* __restrict__ vn) {
    size_t i = ((size_t)blockIdx.x * 256 + threadIdx.x) * 8;  // flat [b][h][t]
    int t0 = (int)(i & (Tn - 1));
    int b = (int)(i >> 19);
    const float* mrb = mr + (size_t)b * Tn + t0;
    ushort4 v0 = *reinterpret_cast<const ushort4*>(vT + i);
    ushort4 v1 = *reinterpret_cast<const ushort4*>(vT + i + 4);
    float4 s0 = *reinterpret_cast<const float4*>(mrb);
    float4 s1 = *reinterpret_cast<const float4*>(mrb + 4);
    unsigned o[4];
    o[0] = cvtpk(b2f(v0.x) * EXP2F(-s0.x), b2f(v0.y) * EXP2F(-s0.y));
    o[1] = cvtpk(b2f(v0.z) * EXP2F(-s0.z), b2f(v0.w) * EXP2F(-s0.w));
    o[2] = cvtpk(b2f(v1.x) * EXP2F(-s1.x), b2f(v1.y) * EXP2F(-s1.y));
    o[3] = cvtpk(b2f(v1.z) * EXP2F(-s1.z), b2f(v1.w) * EXP2F(-s1.w));
    *reinterpret_cast<u32x4*>(vn + i) = *reinterpret_cast<u32x4*>(o);
}

// ---------------- K4: fused attn — 2 q-tiles share K/V stream; k-split -------
__global__ __launch_bounds__(256, 2) void attn_pv(const unsigned short* __restrict__ qs,
                                                  const unsigned short* __restrict__ ks,
                                                  const unsigned short* __restrict__ vn,
                                                  float* __restrict__ opart) {
    // LDS: K dbuf 0..32768 | V dbuf 32768..65536 | P0 65536..73728 | P1 73728..81920
    __shared__ __align__(16) char smem[81920];
    const int bid = blockIdx.x;
    const int b = bid & 7;
    const int rest = bid >> 3;
    const int qp = rest & 31;
    const int kh = rest >> 5;
    const int kbase = kh * 2048;
    const unsigned short* qg = qs + (size_t)b * Tn * Hn;
    const unsigned short* kg = ks + (size_t)b * Tn * Hn;
    const unsigned short* vg = vn + (size_t)b * Hn * Tn;
    const int t = threadIdx.x;
    const int lane = t & 63, wid = t >> 6;
    const int wk = wid >> 1, wq = wid & 1;
    const int fr = lane & 15, fq = lane >> 4;
    const int srow16 = t >> 4, schk16 = t & 15;
    const int srow8 = t >> 3, schk8 = t & 7;

    bf16x8 bq[2][2][4];
    #pragma unroll
    for (int qt = 0; qt < 2; ++qt) {
        int qb0 = qp * 64 + qt * 2048;
        #pragma unroll
        for (int ni = 0; ni < 2; ++ni)
            #pragma unroll
            for (int kc = 0; kc < 4; ++kc) {
                int row = qb0 + wq * 32 + ni * 16 + fr;
                bq[qt][ni][kc] = *reinterpret_cast<const bf16x8*>(
                    &qg[(size_t)row * Hn + kc * 32 + fq * 8]);
            }
    }
    #pragma unroll
    for (int it = 0; it < 4; ++it) {
        int r = it * 16 + srow16;
        gload16(&kg[(size_t)(kbase + r) * Hn + ((schk16 ^ (r & 15)) * 8)],
                smem + it * 4096 + t * 16);
        int rv = it * 32 + srow8;
        gload16(&vg[(size_t)rv * Tn + kbase + ((schk8 ^ (rv & 7)) * 8)],
                smem + 32768 + it * 4096 + t * 16);
    }
    __syncthreads();

    f32x4 acc_o[2][4][2] = {};
    for (int s = 0; s < 32; ++s) {
        const int cur = s & 1;
        {
            const int knr = kbase + ((s + 1) & 31) * 64;
            #pragma unroll
            for (int it = 0; it < 4; ++it) {
                int r = it * 16 + srow16;
                gload16(&kg[(size_t)(knr + r) * Hn + ((schk16 ^ (r & 15)) * 8)],
                        smem + (cur ^ 1) * 16384 + it * 4096 + t * 16);
                int rv = it * 32 + srow8;
                gload16(&vg[(size_t)rv * Tn + knr + ((schk8 ^ (rv & 7)) * 8)],
                        smem + 32768 + (cur ^ 1) * 16384 + it * 4096 + t * 16);
            }
        }
        WAIT_VM_PUB(8);
        const char* Kc = smem + cur * 16384;
        #pragma unroll
        for (int qt = 0; qt < 2; ++qt) {
            char* Pb = smem + 65536 + qt * 8192;
            f32x4 acc_s[2][2] = {};
            __builtin_amdgcn_s_setprio(1);
            #pragma unroll
            for (int kc = 0; kc < 4; ++kc) {
                bf16x8 avk[2];
                #pragma unroll
                for (int mi = 0; mi < 2; ++mi) {
                    int row = wk * 32 + mi * 16 + fr;
                    int ch = (kc * 4 + fq) ^ (row & 15);
                    avk[mi] = *reinterpret_cast<const bf16x8*>(Kc + row * 256 + ch * 16);
                }
                #pragma unroll
                for (int mi = 0; mi < 2; ++mi)
                    #pragma unroll
                    for (int ni = 0; ni < 2; ++ni)
                        acc_s[mi][ni] = MFMA16(avk[mi], bq[qt][ni][kc], acc_s[mi][ni]);
            }
            __builtin_amdgcn_s_setprio(0);
            #pragma unroll
            for (int mi = 0; mi < 2; ++mi)
                #pragma unroll
                for (int ni = 0; ni < 2; ++ni) {
                    float e0 = EXP2F(acc_s[mi][ni][0]);
                    float e1 = EXP2F(acc_s[mi][ni][1]);
                    float e2 = EXP2F(acc_s[mi][ni][2]);
                    float e3 = EXP2F(acc_s[mi][ni][3]);
                    int q = wq * 32 + ni * 16 + fr;
                    int chunk = (wk * 4 + mi * 2 + (fq >> 1)) ^ (q & 7);
                    *reinterpret_cast<uint2*>(Pb + q * 128 + chunk * 16 + (fq & 1) * 8) =
                        make_uint2(cvtpk(e0, e1), cvtpk(e2, e3));
                }
        }
        LGKM_BARRIER();
        const char* Vc = smem + 32768 + cur * 16384;
        __builtin_amdgcn_s_setprio(1);
        #pragma unroll
        for (int kc = 0; kc < 2; ++kc) {
            bf16x8 bp[2][2];
            #pragma unroll
            for (int qt = 0; qt < 2; ++qt)
                #pragma unroll
                for (int ni = 0; ni < 2; ++ni) {
                    int qrow = wq * 32 + ni * 16 + fr;
                    int ch = (kc * 4 + fq) ^ (qrow & 7);
                    bp[qt][ni] = *reinterpret_cast<const bf16x8*>(
                        smem + 65536 + qt * 8192 + qrow * 128 + ch * 16);
                }
            #pragma unroll
            for (int mi = 0; mi < 4; ++mi) {
                int row = wk * 64 + mi * 16 + fr;
                int ch = (kc * 4 + fq) ^ (row & 7);
                bf16x8 avv = *reinterpret_cast<const bf16x8*>(Vc + row * 128 + ch * 16);
                #pragma unroll
                for (int qt = 0; qt < 2; ++qt)
                    #pragma unroll
                    for (int ni = 0; ni < 2; ++ni)
                        acc_o[qt][mi][ni] = MFMA16(avv, bp[qt][ni], acc_o[qt][mi][ni]);
            }
        }
        __builtin_amdgcn_s_setprio(0);
        LGKM_BARRIER();
    }

    float* Ol = (float*)smem;   // [64][132]
    __syncthreads();
    float* op = opart + (size_t)kh * Bn * Tn * Hn + (size_t)b * Tn * Hn;
    #pragma unroll
    for (int qt = 0; qt < 2; ++qt) {
        #pragma unroll
        for (int mi = 0; mi < 4; ++mi)
            #pragma unroll
            for (int ni = 0; ni < 2; ++ni) {
                int q = wq * 32 + ni * 16 + fr;
                int h = wk * 64 + mi * 16 + fq * 4;
                *reinterpret_cast<float4*>(&Ol[q * 132 + h]) =
                    make_float4(acc_o[qt][mi][ni][0], acc_o[qt][mi][ni][1],
                                acc_o[qt][mi][ni][2], acc_o[qt][mi][ni][3]);
            }
        __syncthreads();
        int qrow0 = qp * 64 + qt * 2048;
        #pragma unroll
        for (int j = 0; j < 8; ++j) {
            int idx = j * 256 + t;
            int row = idx >> 5, c = (idx & 31) * 4;
            *reinterpret_cast<float4*>(&op[(size_t)(qrow0 + row) * Hn + c]) =
                *reinterpret_cast<const float4*>(&Ol[row * 132 + c]);
        }
        __syncthreads();
    }
}

// ---------------- K5: out = opart[0] + opart[1] ------------------------------
__global__ __launch_bounds__(256) void combine(const float* __restrict__ opart,
                                               float* __restrict__ out) {
    size_t i = ((size_t)blockIdx.x * 256 + threadIdx.x) * 4;
    const size_t half = (size_t)Bn * Tn * Hn;
    float4 a = *reinterpret_cast<const float4*>(opart + i);
    float4 b = *reinterpret_cast<const float4*>(opart + half + i);
    *reinterpret_cast<float4*>(out + i) =
        make_float4(a.x + b.x, a.y + b.y, a.z + b.z, a.w + b.w);
}

extern "C" void kernel_launch(void* const* d_in, const int* in_sizes, int n_in,
                              void* d_out, int out_size, void* d_ws, size_t ws_size,
                              hipStream_t stream) {
    const float* x  = (const float*)d_in[0];
    const float* Wq = (const float*)d_in[1];
    const float* Wk = (const float*)d_in[2];
    const float* Wv = (const float*)d_in[3];
    float* out = (float*)d_out;

    char* p = (char*)d_ws;
    unsigned short* qs = (unsigned short*)p; p += (size_t)Bn * Tn * Hn * 2;
    unsigned short* ks = (unsigned short*)p; p += (size_t)Bn * Tn * Hn * 2;
    unsigned short* vT = (unsigned short*)p; p += (size_t)Bn * Tn * Hn * 2;
    unsigned short* vn = (unsigned short*)p; p += (size_t)Bn * Tn * Hn * 2;
    unsigned short* Wt = (unsigned short*)p; p += (size_t)3 * En * Hn * 2;
    float2* part       = (float2*)p;         p += (size_t)Bn * Tn * 4 * sizeof(float2);
    float* mr          = (float*)p;          p += (size_t)Bn * Tn * sizeof(float);
    float* opart       = (float*)p;          p += (size_t)2 * Bn * Tn * Hn * sizeof(float);
    size_t needed = (size_t)(p - (char*)d_ws);
    if (ws_size < needed) return;

    prep_w<<<dim3(3 * En * Hn / 256), dim3(256), 0, stream>>>(Wq, Wk, Wv, Wt);
    qkv_mfma<<<dim3((Bn * Tn / 128) * 3), dim3(256), 0, stream>>>(x, Wt, qs, ks, vT);
    stats_qk<<<dim3(512), dim3(256), 0, stream>>>(qs, ks, part);
    stats_comb<<<dim3(Bn * Tn / 256), dim3(256), 0, stream>>>(part, mr);
    scale_v<<<dim3((size_t)Bn * Hn * Tn / (256 * 8)), dim3(256), 0, stream>>>(vT, mr, vn);
    attn_pv<<<dim3(512), dim3(256), 0, stream>>>(qs, ks, vn, opart);
    combine<<<dim3((size_t)Bn * Tn * Hn / (256 * 4)), dim3(256), 0, stream>>>(opart, out);
}

// Round 16
// 240.395 us; speedup vs baseline: 1.1999x; 1.1999x over previous
//
#include <hip/hip_runtime.h>
#include <hip/hip_bf16.h>
#include <hip/hip_fp16.h>

#define Bn 8
#define Tn 4096
#define En 2048
#define Hn 128

typedef __attribute__((ext_vector_type(8))) short bf16x8;
typedef __attribute__((ext_vector_type(4))) float f32x4;
typedef __attribute__((ext_vector_type(4))) unsigned int u32x4;

typedef const __attribute__((address_space(1))) unsigned int* gptr_t;
typedef __attribute__((address_space(3))) unsigned int* lptr_t;

static __device__ __forceinline__ void gload16(const void* g, void* l) {
    __builtin_amdgcn_global_load_lds((gptr_t)g, (lptr_t)l, 16, 0, 0);
}

static __device__ __forceinline__ unsigned short f2bf(float f) {
    union { float f; unsigned u; } v; v.f = f;
    unsigned r = v.u + 0x7FFFu + ((v.u >> 16) & 1u);
    return (unsigned short)(r >> 16);
}
static __device__ __forceinline__ float b2f(unsigned short bits) {
    union { unsigned u; float f; } v; v.u = ((unsigned)bits) << 16;
    return v.f;
}
static __device__ __forceinline__ unsigned cvtpk(float lo, float hi) {
    unsigned r;
    asm volatile("v_cvt_pk_bf16_f32 %0, %1, %2" : "=v"(r) : "v"(lo), "v"(hi));
    return r;
}

#define MFMA16(a, b, c) __builtin_amdgcn_mfma_f32_16x16x32_bf16((a), (b), (c), 0, 0, 0)
#define EXP2F(x) __builtin_amdgcn_exp2f(x)
#define WAIT_VM_PUB(N) do { asm volatile("s_waitcnt vmcnt(" #N ")" ::: "memory"); \
                            __builtin_amdgcn_sched_barrier(0); \
                            __builtin_amdgcn_s_barrier(); \
                            __builtin_amdgcn_sched_barrier(0); } while (0)
#define LGKM_BARRIER() do { asm volatile("s_waitcnt lgkmcnt(0)" ::: "memory"); \
                            __builtin_amdgcn_s_barrier(); \
                            __builtin_amdgcn_sched_barrier(0); } while (0)

// ---------------- K0: transpose+convert weights, fold SCALE*log2e into Wq ----
__global__ __launch_bounds__(256) void prep_w(const float* __restrict__ Wq,
                                              const float* __restrict__ Wk,
                                              const float* __restrict__ Wv,
                                              unsigned short* __restrict__ Wt) {
    int idx = blockIdx.x * 256 + threadIdx.x;
    int w = idx / (En * Hn);
    int rem = idx - w * (En * Hn);
    int kx = rem >> 7;
    int n  = rem & 127;
    const float* W = (w == 0) ? Wq : (w == 1) ? Wk : Wv;
    float f = W[rem];
    if (w == 0) f *= (0.17677669529663687f * 1.4426950408889634f); // 32^-0.5 * log2(e)
    Wt[(size_t)w * En * Hn + (size_t)n * En + kx] = f2bf(f);
}

// ---------------- K1: FUSED qkv — x read ONCE, BM=128 x BN=384 ---------------
// 512 thr = 8 waves (2m x 4n), wave tile 64x96, acc[4][6]. LDS 128 KB:
// A dbuf bf16 (fp32->regs->cvt_pk->swizzled write), B dbuf (gload16 preswz).
// Step: issue A(t+1)regs -> issue B(t+1)gloads -> MFMA(cur) -> vmcnt(6)
// -> cvt+write A -> vmcnt(0)+lgkm(0)+barrier.
__global__ __launch_bounds__(512, 2) void qkv_fused(const float* __restrict__ x,
                                                    const unsigned short* __restrict__ Wt,
                                                    unsigned short* __restrict__ qs,
                                                    unsigned short* __restrict__ ks,
                                                    unsigned short* __restrict__ vT) {
    __shared__ __align__(16) unsigned short Al[2][128][64]; // 32 KB
    __shared__ __align__(16) unsigned short Bl[2][384][64]; // 96 KB
    const int m0 = blockIdx.x * 128;
    const int b = m0 >> 12;
    const int tb = m0 & (Tn - 1);
    const int t = threadIdx.x;
    const int lane = t & 63, wid = t >> 6;
    const int wm = wid >> 2, wn = wid & 3;      // 2 x 4 wave grid
    const int fr = lane & 15, fq = lane >> 4;
    // A staging: agrp=t>>4 owns rows agrp*4+j (j<4); aln=t&15 float4-chunk
    const int agrp = t >> 4, aln = t & 15;
    // B staging: 48 segs of 8 rows x 8 chunks; wave owns 6 segs
    const int bR = lane >> 3, bC = lane & 7;

    // prologue: A(0) regs->cvt->LDS, B(0) gloads
    {
        #pragma unroll
        for (int j = 0; j < 4; ++j) {
            int row = agrp * 4 + j;
            float4 v = *reinterpret_cast<const float4*>(&x[(size_t)(m0 + row) * En + aln * 4]);
            int cb = (aln >> 1) ^ (row & 7);
            *reinterpret_cast<uint2*>((char*)&Al[0][0][0] + row * 128 + cb * 16 + (aln & 1) * 8)
                = make_uint2(cvtpk(v.x, v.y), cvtpk(v.z, v.w));
        }
        #pragma unroll
        for (int s_ = 0; s_ < 6; ++s_) {
            int seg = wid * 6 + s_;
            int r = seg * 8 + bR;
            gload16(&Wt[(size_t)r * En + ((bC ^ (r & 7)) * 8)],
                    (char*)&Bl[0][0][0] + seg * 1024 + lane * 16);
        }
    }
    asm volatile("s_waitcnt vmcnt(0) lgkmcnt(0)" ::: "memory");
    __builtin_amdgcn_s_barrier();
    __builtin_amdgcn_sched_barrier(0);

    f32x4 acc[4][6] = {};
    for (int s = 0; s < 32; ++s) {
        const int cur = s & 1;
        const int kn = ((s + 1) & 31) * 64;   // wrap: final prefetch unused
        // 1. A(t+1) -> regs (4 vmem; 16 lanes cover one 256B row)
        float4 ar_[4];
        #pragma unroll
        for (int j = 0; j < 4; ++j) {
            int row = agrp * 4 + j;
            ar_[j] = *reinterpret_cast<const float4*>(&x[(size_t)(m0 + row) * En + kn + aln * 4]);
        }
        __builtin_amdgcn_sched_barrier(0);   // pin A-issue before B-issue (vmcnt FIFO)
        // 2. B(t+1) gloads -> Bl[alt] (6 vmem)
        #pragma unroll
        for (int s_ = 0; s_ < 6; ++s_) {
            int seg = wid * 6 + s_;
            int r = seg * 8 + bR;
            gload16(&Wt[(size_t)r * En + kn + ((bC ^ (r & 7)) * 8)],
                    (char*)&Bl[cur ^ 1][0][0] + seg * 1024 + lane * 16);
        }
        __builtin_amdgcn_sched_barrier(0);
        // 3. MFMA on [cur]
        __builtin_amdgcn_s_setprio(1);
        #pragma unroll
        for (int ksub = 0; ksub < 2; ++ksub) {
            bf16x8 av[4], bv[6];
            #pragma unroll
            for (int mi = 0; mi < 4; ++mi) {
                int row = wm * 64 + mi * 16 + fr;
                int ch = (ksub * 4 + fq) ^ (row & 7);
                av[mi] = *reinterpret_cast<const bf16x8*>(
                    (const char*)&Al[cur][0][0] + row * 128 + ch * 16);
            }
            #pragma unroll
            for (int ni = 0; ni < 6; ++ni) {
                int row = wn * 96 + ni * 16 + fr;
                int ch = (ksub * 4 + fq) ^ (row & 7);
                bv[ni] = *reinterpret_cast<const bf16x8*>(
                    (const char*)&Bl[cur][0][0] + row * 128 + ch * 16);
            }
            #pragma unroll
            for (int mi = 0; mi < 4; ++mi)
                #pragma unroll
                for (int ni = 0; ni < 6; ++ni)
                    acc[mi][ni] = MFMA16(av[mi], bv[ni], acc[mi][ni]);
        }
        __builtin_amdgcn_s_setprio(0);
        // 4. A regs arrived (6 B-gloads still in flight)
        asm volatile("s_waitcnt vmcnt(6)" ::: "memory");
        __builtin_amdgcn_sched_barrier(0);
        // 5. cvt + write A(t+1) -> Al[alt]
        #pragma unroll
        for (int j = 0; j < 4; ++j) {
            int row = agrp * 4 + j;
            int cb = (aln >> 1) ^ (row & 7);
            *reinterpret_cast<uint2*>((char*)&Al[cur ^ 1][0][0] + row * 128 + cb * 16 + (aln & 1) * 8)
                = make_uint2(cvtpk(ar_[j].x, ar_[j].y), cvtpk(ar_[j].z, ar_[j].w));
        }
        // 6. single barrier: B landed, A visible, [cur] reads retired
        asm volatile("s_waitcnt vmcnt(0) lgkmcnt(0)" ::: "memory");
        __builtin_amdgcn_s_barrier();
        __builtin_amdgcn_sched_barrier(0);
    }

    // epilogue: col c selects q / k / vT
    #pragma unroll
    for (int mi = 0; mi < 4; ++mi)
        #pragma unroll
        for (int ni = 0; ni < 6; ++ni) {
            int c = wn * 96 + ni * 16 + fr;
            int w = c >> 7, h = c & 127;
            #pragma unroll
            for (int r = 0; r < 4; ++r) {
                int rloc = wm * 64 + mi * 16 + fq * 4 + r;
                unsigned short val = f2bf(acc[mi][ni][r]);
                if (w == 0)      qs[(size_t)(m0 + rloc) * Hn + h] = val;
                else if (w == 1) ks[(size_t)(m0 + rloc) * Hn + h] = val;
                else             vT[((size_t)b * Hn + h) * Tn + tb + rloc] = val;
            }
        }
}

// ---------------- K2: column stats — 128 stationary keys, Q double-buffered --
__global__ __launch_bounds__(256, 2) void stats_qk(const unsigned short* __restrict__ qs,
                                                   const unsigned short* __restrict__ ks,
                                                   float2* __restrict__ part) {
    // LDS: K 0..32768 | Q dbuf 32768..65536
    __shared__ __align__(16) char smem[65536];
    const int bid = blockIdx.x;
    const int b = bid & 7;
    const int rest = bid >> 3;                // 0..63
    const int kt = rest & 31;
    const int qh = rest >> 5;
    const int k0 = kt * 128;
    const unsigned short* qb = qs + (size_t)b * Tn * Hn;
    const unsigned short* kb = ks + (size_t)b * Tn * Hn;
    const int t = threadIdx.x;
    const int lane = t & 63, wid = t >> 6;
    const int wk = wid >> 1, wq = wid & 1;
    const int fr = lane & 15, fq = lane >> 4;
    const int srow = t >> 4, schk = t & 15;

    #pragma unroll
    for (int it = 0; it < 8; ++it) {
        int r = it * 16 + srow;
        gload16(&kb[(size_t)(k0 + r) * Hn + ((schk ^ (r & 15)) * 8)],
                smem + it * 4096 + t * 16);
    }
    #pragma unroll
    for (int it = 0; it < 4; ++it) {
        int r = it * 16 + srow;
        gload16(&qb[(size_t)(qh * 2048 + r) * Hn + ((schk ^ (r & 15)) * 8)],
                smem + 32768 + it * 4096 + t * 16);
    }
    __syncthreads();
    bf16x8 av[4][4];
    #pragma unroll
    for (int mi = 0; mi < 4; ++mi)
        #pragma unroll
        for (int kc = 0; kc < 4; ++kc) {
            int row = wk * 64 + mi * 16 + fr;
            int ch = (kc * 4 + fq) ^ (row & 15);
            av[mi][kc] = *reinterpret_cast<const bf16x8*>(smem + row * 256 + ch * 16);
        }

    float m[4][4], l[4][4];
    #pragma unroll
    for (int mi = 0; mi < 4; ++mi)
        #pragma unroll
        for (int r = 0; r < 4; ++r) { m[mi][r] = -INFINITY; l[mi][r] = 0.f; }

    for (int step = 0; step < 32; ++step) {
        const int cur = step & 1;
        const int qn = qh * 2048 + ((step + 1) & 31) * 64;
        #pragma unroll
        for (int it = 0; it < 4; ++it) {
            int r = it * 16 + srow;
            gload16(&qb[(size_t)(qn + r) * Hn + ((schk ^ (r & 15)) * 8)],
                    smem + 32768 + (cur ^ 1) * 16384 + it * 4096 + t * 16);
        }
        WAIT_VM_PUB(4);
        const char* Qc = smem + 32768 + cur * 16384;
        f32x4 acc[4][2] = {};
        __builtin_amdgcn_s_setprio(1);
        #pragma unroll
        for (int kc = 0; kc < 4; ++kc) {
            bf16x8 bv[2];
            #pragma unroll
            for (int ni = 0; ni < 2; ++ni) {
                int row = wq * 32 + ni * 16 + fr;
                int ch = (kc * 4 + fq) ^ (row & 15);
                bv[ni] = *reinterpret_cast<const bf16x8*>(Qc + row * 256 + ch * 16);
            }
            #pragma unroll
            for (int mi = 0; mi < 4; ++mi)
                #pragma unroll
                for (int ni = 0; ni < 2; ++ni)
                    acc[mi][ni] = MFMA16(av[mi][kc], bv[ni], acc[mi][ni]);
        }
        __builtin_amdgcn_s_setprio(0);
        #pragma unroll
        for (int mi = 0; mi < 4; ++mi)
            #pragma unroll
            for (int r = 0; r < 4; ++r) {
                float v0 = acc[mi][0][r], v1 = acc[mi][1][r];
                float mn = fmaxf(m[mi][r], fmaxf(v0, v1));
                l[mi][r] = l[mi][r] * EXP2F(m[mi][r] - mn) + EXP2F(v0 - mn) + EXP2F(v1 - mn);
                m[mi][r] = mn;
            }
        LGKM_BARRIER();
    }
    #pragma unroll
    for (int off = 1; off <= 8; off <<= 1) {
        #pragma unroll
        for (int mi = 0; mi < 4; ++mi)
            #pragma unroll
            for (int r = 0; r < 4; ++r) {
                float mo = __shfl_xor(m[mi][r], off);
                float lo = __shfl_xor(l[mi][r], off);
                float mn = fmaxf(m[mi][r], mo);
                l[mi][r] = l[mi][r] * EXP2F(m[mi][r] - mn) + lo * EXP2F(mo - mn);
                m[mi][r] = mn;
            }
    }
    if (fr == 0) {
        #pragma unroll
        for (int mi = 0; mi < 4; ++mi)
            #pragma unroll
            for (int r = 0; r < 4; ++r) {
                int k = k0 + wk * 64 + mi * 16 + fq * 4 + r;
                part[((size_t)b * Tn + k) * 4 + qh * 2 + wq] = make_float2(m[mi][r], l[mi][r]);
            }
    }
}

// ---------------- K3: combine 4 partials -> mr[b][k] = m + log2(l) -----------
__global__ __launch_bounds__(256) void stats_comb(const float2* __restrict__ part,
                                                  float* __restrict__ mr) {
    int g = blockIdx.x * 256 + threadIdx.x;   // 8*4096
    const float2* pp = part + (size_t)g * 4;
    float2 p0 = pp[0], p1 = pp[1], p2 = pp[2], p3 = pp[3];
    float M = fmaxf(fmaxf(p0.x, p1.x), fmaxf(p2.x, p3.x));
    float L = p0.y * EXP2F(p0.x - M) + p1.y * EXP2F(p1.x - M) +
              p2.y * EXP2F(p2.x - M) + p3.y * EXP2F(p3.x - M);
    mr[g] = M + __log2f(L);
}

// ---------------- K3b: vn[b][h][t] = v * 2^(-mr[b][t]) -----------------------
__global__ __launch_bounds__(256) void scale_v(const unsigned short* __restrict__ vT,
                                               const float* __restrict__ mr,
                                               unsigned short* __restrict__ vn) {
    size_t i = ((size_t)blockIdx.x * 256 + threadIdx.x) * 8;  // flat [b][h][t]
    int t0 = (int)(i & (Tn - 1));
    int b = (int)(i >> 19);
    const float* mrb = mr + (size_t)b * Tn + t0;
    ushort4 v0 = *reinterpret_cast<const ushort4*>(vT + i);
    ushort4 v1 = *reinterpret_cast<const ushort4*>(vT + i + 4);
    float4 s0 = *reinterpret_cast<const float4*>(mrb);
    float4 s1 = *reinterpret_cast<const float4*>(mrb + 4);
    unsigned o[4];
    o[0] = cvtpk(b2f(v0.x) * EXP2F(-s0.x), b2f(v0.y) * EXP2F(-s0.y));
    o[1] = cvtpk(b2f(v0.z) * EXP2F(-s0.z), b2f(v0.w) * EXP2F(-s0.w));
    o[2] = cvtpk(b2f(v1.x) * EXP2F(-s1.x), b2f(v1.y) * EXP2F(-s1.y));
    o[3] = cvtpk(b2f(v1.z) * EXP2F(-s1.z), b2f(v1.w) * EXP2F(-s1.w));
    *reinterpret_cast<u32x4*>(vn + i) = *reinterpret_cast<u32x4*>(o);
}

// ---------------- K4: fused attn — 2 q-tiles share K/V stream; k-split -------
__global__ __launch_bounds__(256, 2) void attn_pv(const unsigned short* __restrict__ qs,
                                                  const unsigned short* __restrict__ ks,
                                                  const unsigned short* __restrict__ vn,
                                                  float* __restrict__ opart) {
    // LDS: K dbuf 0..32768 | V dbuf 32768..65536 | P0 65536..73728 | P1 73728..81920
    __shared__ __align__(16) char smem[81920];
    const int bid = blockIdx.x;
    const int b = bid & 7;
    const int rest = bid >> 3;
    const int qp = rest & 31;
    const int kh = rest >> 5;
    const int kbase = kh * 2048;
    const unsigned short* qg = qs + (size_t)b * Tn * Hn;
    const unsigned short* kg = ks + (size_t)b * Tn * Hn;
    const unsigned short* vg = vn + (size_t)b * Hn * Tn;
    const int t = threadIdx.x;
    const int lane = t & 63, wid = t >> 6;
    const int wk = wid >> 1, wq = wid & 1;
    const int fr = lane & 15, fq = lane >> 4;
    const int srow16 = t >> 4, schk16 = t & 15;
    const int srow8 = t >> 3, schk8 = t & 7;

    bf16x8 bq[2][2][4];
    #pragma unroll
    for (int qt = 0; qt < 2; ++qt) {
        int qb0 = qp * 64 + qt * 2048;
        #pragma unroll
        for (int ni = 0; ni < 2; ++ni)
            #pragma unroll
            for (int kc = 0; kc < 4; ++kc) {
                int row = qb0 + wq * 32 + ni * 16 + fr;
                bq[qt][ni][kc] = *reinterpret_cast<const bf16x8*>(
                    &qg[(size_t)row * Hn + kc * 32 + fq * 8]);
            }
    }
    #pragma unroll
    for (int it = 0; it < 4; ++it) {
        int r = it * 16 + srow16;
        gload16(&kg[(size_t)(kbase + r) * Hn + ((schk16 ^ (r & 15)) * 8)],
                smem + it * 4096 + t * 16);
        int rv = it * 32 + srow8;
        gload16(&vg[(size_t)rv * Tn + kbase + ((schk8 ^ (rv & 7)) * 8)],
                smem + 32768 + it * 4096 + t * 16);
    }
    __syncthreads();

    f32x4 acc_o[2][4][2] = {};
    for (int s = 0; s < 32; ++s) {
        const int cur = s & 1;
        {
            const int knr = kbase + ((s + 1) & 31) * 64;
            #pragma unroll
            for (int it = 0; it < 4; ++it) {
                int r = it * 16 + srow16;
                gload16(&kg[(size_t)(knr + r) * Hn + ((schk16 ^ (r & 15)) * 8)],
                        smem + (cur ^ 1) * 16384 + it * 4096 + t * 16);
                int rv = it * 32 + srow8;
                gload16(&vg[(size_t)rv * Tn + knr + ((schk8 ^ (rv & 7)) * 8)],
                        smem + 32768 + (cur ^ 1) * 16384 + it * 4096 + t * 16);
            }
        }
        WAIT_VM_PUB(8);
        const char* Kc = smem + cur * 16384;
        #pragma unroll
        for (int qt = 0; qt < 2; ++qt) {
            char* Pb = smem + 65536 + qt * 8192;
            f32x4 acc_s[2][2] = {};
            __builtin_amdgcn_s_setprio(1);
            #pragma unroll
            for (int kc = 0; kc < 4; ++kc) {
                bf16x8 avk[2];
                #pragma unroll
                for (int mi = 0; mi < 2; ++mi) {
                    int row = wk * 32 + mi * 16 + fr;
                    int ch = (kc * 4 + fq) ^ (row & 15);
                    avk[mi] = *reinterpret_cast<const bf16x8*>(Kc + row * 256 + ch * 16);
                }
                #pragma unroll
                for (int mi = 0; mi < 2; ++mi)
                    #pragma unroll
                    for (int ni = 0; ni < 2; ++ni)
                        acc_s[mi][ni] = MFMA16(avk[mi], bq[qt][ni][kc], acc_s[mi][ni]);
            }
            __builtin_amdgcn_s_setprio(0);
            #pragma unroll
            for (int mi = 0; mi < 2; ++mi)
                #pragma unroll
                for (int ni = 0; ni < 2; ++ni) {
                    float e0 = EXP2F(acc_s[mi][ni][0]);
                    float e1 = EXP2F(acc_s[mi][ni][1]);
                    float e2 = EXP2F(acc_s[mi][ni][2]);
                    float e3 = EXP2F(acc_s[mi][ni][3]);
                    int q = wq * 32 + ni * 16 + fr;
                    int chunk = (wk * 4 + mi * 2 + (fq >> 1)) ^ (q & 7);
                    *reinterpret_cast<uint2*>(Pb + q * 128 + chunk * 16 + (fq & 1) * 8) =
                        make_uint2(cvtpk(e0, e1), cvtpk(e2, e3));
                }
        }
        LGKM_BARRIER();
        const char* Vc = smem + 32768 + cur * 16384;
        __builtin_amdgcn_s_setprio(1);
        #pragma unroll
        for (int kc = 0; kc < 2; ++kc) {
            bf16x8 bp[2][2];
            #pragma unroll
            for (int qt = 0; qt < 2; ++qt)
                #pragma unroll
                for (int ni = 0; ni < 2; ++ni) {
                    int qrow = wq * 32 + ni * 16 + fr;
                    int ch = (kc * 4 + fq) ^ (qrow & 7);
                    bp[qt][ni] = *reinterpret_cast<const bf16x8*>(
                        smem + 65536 + qt * 8192 + qrow * 128 + ch * 16);
                }
            #pragma unroll
            for (int mi = 0; mi < 4; ++mi) {
                int row = wk * 64 + mi * 16 + fr;
                int ch = (kc * 4 + fq) ^ (row & 7);
                bf16x8 avv = *reinterpret_cast<const bf16x8*>(Vc + row * 128 + ch * 16);
                #pragma unroll
                for (int qt = 0; qt < 2; ++qt)
                    #pragma unroll
                    for (int ni = 0; ni < 2; ++ni)
                        acc_o[qt][mi][ni] = MFMA16(avv, bp[qt][ni], acc_o[qt][mi][ni]);
            }
        }
        __builtin_amdgcn_s_setprio(0);
        LGKM_BARRIER();
    }

    float* Ol = (float*)smem;   // [64][132]
    __syncthreads();
    float* op = opart + (size_t)kh * Bn * Tn * Hn + (size_t)b * Tn * Hn;
    #pragma unroll
    for (int qt = 0; qt < 2; ++qt) {
        #pragma unroll
        for (int mi = 0; mi < 4; ++mi)
            #pragma unroll
            for (int ni = 0; ni < 2; ++ni) {
                int q = wq * 32 + ni * 16 + fr;
                int h = wk * 64 + mi * 16 + fq * 4;
                *reinterpret_cast<float4*>(&Ol[q * 132 + h]) =
                    make_float4(acc_o[qt][mi][ni][0], acc_o[qt][mi][ni][1],
                                acc_o[qt][mi][ni][2], acc_o[qt][mi][ni][3]);
            }
        __syncthreads();
        int qrow0 = qp * 64 + qt * 2048;
        #pragma unroll
        for (int j = 0; j < 8; ++j) {
            int idx = j * 256 + t;
            int row = idx >> 5, c = (idx & 31) * 4;
            *reinterpret_cast<float4*>(&op[(size_t)(qrow0 + row) * Hn + c]) =
                *reinterpret_cast<const float4*>(&Ol[row * 132 + c]);
        }
        __syncthreads();
    }
}

// ---------------- K5: out = opart[0] + opart[1] ------------------------------
__global__ __launch_bounds__(256) void combine(const float* __restrict__ opart,
                                               float* __restrict__ out) {
    size_t i = ((size_t)blockIdx.x * 256 + threadIdx.x) * 4;
    const size_t half = (size_t)Bn * Tn * Hn;
    float4 a = *reinterpret_cast<const float4*>(opart + i);
    float4 b = *reinterpret_cast<const float4*>(opart + half + i);
    *reinterpret_cast<float4*>(out + i) =
        make_float4(a.x + b.x, a.y + b.y, a.z + b.z, a.w + b.w);
}

extern "C" void kernel_launch(void* const* d_in, const int* in_sizes, int n_in,
                              void* d_out, int out_size, void* d_ws, size_t ws_size,
                              hipStream_t stream) {
    const float* x  = (const float*)d_in[0];
    const float* Wq = (const float*)d_in[1];
    const float* Wk = (const float*)d_in[2];
    const float* Wv = (const float*)d_in[3];
    float* out = (float*)d_out;

    char* p = (char*)d_ws;
    unsigned short* qs = (unsigned short*)p; p += (size_t)Bn * Tn * Hn * 2;
    unsigned short* ks = (unsigned short*)p; p += (size_t)Bn * Tn * Hn * 2;
    unsigned short* vT = (unsigned short*)p; p += (size_t)Bn * Tn * Hn * 2;
    unsigned short* vn = (unsigned short*)p; p += (size_t)Bn * Tn * Hn * 2;
    unsigned short* Wt = (unsigned short*)p; p += (size_t)3 * En * Hn * 2;
    float2* part       = (float2*)p;         p += (size_t)Bn * Tn * 4 * sizeof(float2);
    float* mr          = (float*)p;          p += (size_t)Bn * Tn * sizeof(float);
    float* opart       = (float*)p;          p += (size_t)2 * Bn * Tn * Hn * sizeof(float);
    size_t needed = (size_t)(p - (char*)d_ws);
    if (ws_size < needed) return;

    prep_w<<<dim3(3 * En * Hn / 256), dim3(256), 0, stream>>>(Wq, Wk, Wv, Wt);
    qkv_fused<<<dim3(Bn * Tn / 128), dim3(512), 0, stream>>>(x, Wt, qs, ks, vT);
    stats_qk<<<dim3(512), dim3(256), 0, stream>>>(qs, ks, part);
    stats_comb<<<dim3(Bn * Tn / 256), dim3(256), 0, stream>>>(part, mr);
    scale_v<<<dim3((size_t)Bn * Hn * Tn / (256 * 8)), dim3(256), 0, stream>>>(vT, mr, vn);
    attn_pv<<<dim3(512), dim3(256), 0, stream>>>(qs, ks, vn, opart);
    combine<<<dim3((size_t)Bn * Tn * Hn / (256 * 4)), dim3(256), 0, stream>>>(opart, out);
}